// Round 4
// baseline (597.081 us; speedup 1.0000x reference)
//
#include <hip/hip_runtime.h>
#include <hip/hip_bf16.h>

// CoarsenLattice forward: out[Nc,128] = gather(fine, nbr)[Nc, 9*64] @ W[576,128]
// Round 4: W fully LDS-resident (144 KB, staged once per block), barrier-free
// main loop. Each wave independently streams 16 rows x 9 neighbors with
// depth-2 register prefetch. Grid 512 blocks x 4 M-tiles.

#define N_FINE   1048576
#define N_COARSE 262144
#define VAL_DIM  64
#define FE       9
#define NF       128
#define THREADS  512
#define TILES    4            // 4 * 128 rows per block

typedef __attribute__((ext_vector_type(8))) short bf16x8;
typedef __attribute__((ext_vector_type(4))) float f32x4;

__device__ __forceinline__ unsigned short f2bf(float f) {
    unsigned u = __float_as_uint(f);
    return (unsigned short)((u + 0x7FFFu + ((u >> 16) & 1u)) >> 16);
}

// W prep: wTswz is FE tiles of 8192 ushorts (16 KB each). The byte stream is
// the LDS image: logical chunk (col,kc) of tile fe lives at byte
// col*128 + ((kc*16) ^ ((col&7)<<4)). Iterate dest-linear, unswizzle.
__global__ void prep_wt_kernel(const float* __restrict__ w,
                               unsigned short* __restrict__ wTswz) {
    int i = blockIdx.x * 256 + threadIdx.x;     // over FE*8192 = 73728 ushorts
    if (i >= FE * 8192) return;
    int fe   = i >> 13;
    int r    = i & 8191;
    int byte = r * 2;
    int col  = byte >> 7;                       // 0..127
    int b0   = (byte & 127) ^ ((col & 7) << 4); // unswizzled byte within row
    int k    = fe * 64 + (b0 >> 1);
    wTswz[i] = f2bf(w[(size_t)k * NF + col]);
}

__launch_bounds__(THREADS, 2)
__global__ void coarsen_kernel(const float* __restrict__ fine,
                               const int* __restrict__ nbr,
                               const unsigned short* __restrict__ wTswz,
                               float* __restrict__ out) {
    __shared__ __align__(16) unsigned short sW[FE * 8192];   // 144 KB

    const int t    = threadIdx.x;
    const int wave = t >> 6;
    const int lane = t & 63;
    const int l15  = lane & 15;
    const int lhi  = lane >> 4;
    const int bRow = blockIdx.x * (TILES * 128);

    // ---- stage ALL of W once: 9216 x 16B chunks via global_load_lds ----
#pragma unroll
    for (int c = 0; c < 18; ++c) {
        const char* gs = (const char*)wTswz + (size_t)(c * THREADS + t) * 16;
        char*       ls = (char*)sW + (size_t)(c * THREADS + t) * 16;
        __builtin_amdgcn_global_load_lds(
            (const __attribute__((address_space(1))) void*)gs,
            (__attribute__((address_space(3))) void*)ls, 16, 0, 0);
    }
    asm volatile("s_waitcnt vmcnt(0)" ::: "memory");
    __syncthreads();
    // ---- no synchronization below this line: waves run free ----

    float4 paA[4], paB[4];
    bf16x8 af0, af1;

#define LOAD_A(fe_, P) do {                                                \
    const float* rp_ = fine + (size_t)idx[fe_] * VAL_DIM + lhi * 8;        \
    P[0] = *(const float4*)(rp_);                                          \
    P[1] = *(const float4*)(rp_ + 4);                                      \
    P[2] = *(const float4*)(rp_ + 32);                                     \
    P[3] = *(const float4*)(rp_ + 36);                                     \
} while (0)

#define CONV_A(P) do {                                                     \
    union { bf16x8 v; unsigned short u[8]; } c0_, c1_;                     \
    c0_.u[0] = f2bf(P[0].x); c0_.u[1] = f2bf(P[0].y);                      \
    c0_.u[2] = f2bf(P[0].z); c0_.u[3] = f2bf(P[0].w);                      \
    c0_.u[4] = f2bf(P[1].x); c0_.u[5] = f2bf(P[1].y);                      \
    c0_.u[6] = f2bf(P[1].z); c0_.u[7] = f2bf(P[1].w);                      \
    c1_.u[0] = f2bf(P[2].x); c1_.u[1] = f2bf(P[2].y);                      \
    c1_.u[2] = f2bf(P[2].z); c1_.u[3] = f2bf(P[2].w);                      \
    c1_.u[4] = f2bf(P[3].x); c1_.u[5] = f2bf(P[3].y);                      \
    c1_.u[6] = f2bf(P[3].z); c1_.u[7] = f2bf(P[3].w);                      \
    af0 = c0_.v; af1 = c1_.v;                                              \
} while (0)

#define COMPUTE(fe_) do {                                                  \
    _Pragma("unroll")                                                      \
    for (int ks = 0; ks < 2; ++ks) {                                       \
        const bf16x8 a = ks ? af1 : af0;                                   \
        const int off = ks * 64 + lhi * 16;                                \
        _Pragma("unroll")                                                  \
        for (int fn = 0; fn < 8; ++fn) {                                   \
            const int col = fn * 16 + l15;                                 \
            const bf16x8 b = *(const bf16x8*)(                             \
                (const char*)sW + (fe_) * 16384 + col * 128 +              \
                (off ^ ((col & 7) << 4)));                                 \
            acc[fn] = __builtin_amdgcn_mfma_f32_16x16x32_bf16(             \
                a, b, acc[fn], 0, 0, 0);                                   \
        }                                                                  \
    }                                                                      \
} while (0)

// STEP(fe): consume buffer (fe&1), refill it with fe+2, compute fe.
#define STEP(fe_, P) do {                                                  \
    CONV_A(P);                                                             \
    if ((fe_) + 2 < FE) LOAD_A((fe_) + 2, P);                              \
    COMPUTE(fe_);                                                          \
} while (0)

    for (int tile = 0; tile < TILES; ++tile) {
        const int rowBase = bRow + tile * 128;
        const int myRow   = rowBase + wave * 16 + l15;

        int idx[FE];
        {
            const int* nb = nbr + (size_t)myRow * FE;
#pragma unroll
            for (int f = 0; f < FE; ++f) idx[f] = nb[f];
        }

        f32x4 acc[8];
#pragma unroll
        for (int i = 0; i < 8; ++i) acc[i] = (f32x4)0.0f;

        LOAD_A(0, paA);
        LOAD_A(1, paB);

        STEP(0, paA);
        STEP(1, paB);
        STEP(2, paA);
        STEP(3, paB);
        STEP(4, paA);
        STEP(5, paB);
        STEP(6, paA);
        STEP(7, paB);
        STEP(8, paA);

        // epilogue: C[row = lhi*4+j][col = l15] per 16x16 frag
#pragma unroll
        for (int fn = 0; fn < 8; ++fn)
#pragma unroll
            for (int j = 0; j < 4; ++j) {
                const int row = rowBase + wave * 16 + lhi * 4 + j;
                const int col = fn * 16 + l15;
                out[(size_t)row * NF + col] = acc[fn][j];
            }
    }

#undef LOAD_A
#undef CONV_A
#undef COMPUTE
#undef STEP
}

extern "C" void kernel_launch(void* const* d_in, const int* in_sizes, int n_in,
                              void* d_out, int out_size, void* d_ws, size_t ws_size,
                              hipStream_t stream) {
    const float* fine = (const float*)d_in[0];
    const int*   nbr  = (const int*)d_in[1];
    const float* w    = (const float*)d_in[2];
    float* out = (float*)d_out;

    unsigned short* wTswz = (unsigned short*)d_ws;   // FE*8192 ushorts = 144 KB

    prep_wt_kernel<<<(FE * 8192 + 255) / 256, 256, 0, stream>>>(w, wTswz);
    coarsen_kernel<<<N_COARSE / (TILES * 128), THREADS, 0, stream>>>(fine, nbr, wTswz, out);
}

// Round 5
// 127.152 us; speedup vs baseline: 4.6958x; 4.6958x over previous
//
#include <hip/hip_runtime.h>
#include <hip/hip_bf16.h>

// CoarsenLattice forward: out[Nc,128] = gather(fine, nbr)[Nc, 9*64] @ W[576,128]
// Round 5 = Round 3 + nontemporal output stores / index loads (cache-pollution
// control). Round 3 structure: reg-gathered A (wave owns 16 rows), W staged
// per-fe via global_load_lds double-buffer, counted vmcnt keeps A-gathers in
// flight across the one barrier per fe.

#define N_FINE   1048576
#define N_COARSE 262144
#define VAL_DIM  64
#define FE       9
#define NF       128
#define BM       128              // 8 waves * 16 rows
#define THREADS  512

typedef __attribute__((ext_vector_type(8))) short bf16x8;
typedef __attribute__((ext_vector_type(4))) float f32x4;

__device__ __forceinline__ unsigned short f2bf(float f) {
    unsigned u = __float_as_uint(f);
    return (unsigned short)((u + 0x7FFFu + ((u >> 16) & 1u)) >> 16);
}

// W prep: wTswz is FE tiles of 8192 ushorts (16 KB). Byte stream is the LDS
// image: logical chunk (col,kc) lives at byte col*128 + ((kc*16)^((col&7)<<4)).
__global__ void prep_wt_kernel(const float* __restrict__ w,
                               unsigned short* __restrict__ wTswz) {
    int i = blockIdx.x * 256 + threadIdx.x;     // over FE*8192 = 73728 ushorts
    if (i >= FE * 8192) return;
    int fe   = i >> 13;
    int r    = i & 8191;
    int byte = r * 2;
    int col  = byte >> 7;                       // 0..127
    int b0   = (byte & 127) ^ ((col & 7) << 4); // unswizzled byte within row
    int k    = fe * 64 + (b0 >> 1);
    wTswz[i] = f2bf(w[(size_t)k * NF + col]);
}

__launch_bounds__(THREADS, 4)
__global__ void coarsen_kernel(const float* __restrict__ fine,
                               const int* __restrict__ nbr,
                               const unsigned short* __restrict__ wTswz,
                               float* __restrict__ out) {
    __shared__ __align__(16) unsigned short sW[2][8192];   // 2 x 16 KB

    const int t    = threadIdx.x;
    const int wave = t >> 6;
    const int lane = t & 63;
    const int l15  = lane & 15;
    const int lhi  = lane >> 4;
    const int bRow = blockIdx.x * BM;
    const int myRow = bRow + wave * 16 + l15;

    // hoist all 9 neighbor indices into registers (single-use stream: NT loads)
    int idx[FE];
    {
        const int* nb = nbr + (size_t)myRow * FE;
#pragma unroll
        for (int f = 0; f < FE; ++f) idx[f] = __builtin_nontemporal_load(nb + f);
    }

    f32x4 acc[8];
#pragma unroll
    for (int i = 0; i < 8; ++i) acc[i] = (f32x4)0.0f;

    float4 pa[4];        // prefetched A row chunk
    bf16x8 af0, af1;     // current A fragments (ks=0,1)

#define LOAD_A(fe_) do {                                                   \
    const float* rp_ = fine + (size_t)idx[fe_] * VAL_DIM + lhi * 8;        \
    pa[0] = *(const float4*)(rp_);                                         \
    pa[1] = *(const float4*)(rp_ + 4);                                     \
    pa[2] = *(const float4*)(rp_ + 32);                                    \
    pa[3] = *(const float4*)(rp_ + 36);                                    \
} while (0)

#define STAGE_W(fe_, buf_) do {                                            \
    const char* gs_ = (const char*)wTswz + (size_t)(fe_) * 16384;          \
    char* ls_ = (char*)&sW[buf_][0];                                       \
    __builtin_amdgcn_global_load_lds(                                      \
        (const __attribute__((address_space(1))) void*)(gs_ + t * 16),     \
        (__attribute__((address_space(3))) void*)(ls_ + t * 16), 16, 0, 0);\
    __builtin_amdgcn_global_load_lds(                                      \
        (const __attribute__((address_space(1))) void*)(gs_ + 8192 + t * 16), \
        (__attribute__((address_space(3))) void*)(ls_ + 8192 + t * 16), 16, 0, 0); \
} while (0)

#define CONV_A() do {                                                      \
    union { bf16x8 v; unsigned short u[8]; } c0_, c1_;                     \
    c0_.u[0] = f2bf(pa[0].x); c0_.u[1] = f2bf(pa[0].y);                    \
    c0_.u[2] = f2bf(pa[0].z); c0_.u[3] = f2bf(pa[0].w);                    \
    c0_.u[4] = f2bf(pa[1].x); c0_.u[5] = f2bf(pa[1].y);                    \
    c0_.u[6] = f2bf(pa[1].z); c0_.u[7] = f2bf(pa[1].w);                    \
    c1_.u[0] = f2bf(pa[2].x); c1_.u[1] = f2bf(pa[2].y);                    \
    c1_.u[2] = f2bf(pa[2].z); c1_.u[3] = f2bf(pa[2].w);                    \
    c1_.u[4] = f2bf(pa[3].x); c1_.u[5] = f2bf(pa[3].y);                    \
    c1_.u[6] = f2bf(pa[3].z); c1_.u[7] = f2bf(pa[3].w);                    \
    af0 = c0_.v; af1 = c1_.v;                                              \
} while (0)

    // ---- prologue: stage fe=0 ----
    STAGE_W(0, 0);
    LOAD_A(0);
    asm volatile("s_waitcnt vmcnt(0)" ::: "memory");
    __syncthreads();

#pragma unroll
    for (int fe = 0; fe < FE; ++fe) {
        const int buf = fe & 1;
        CONV_A();
        if (fe + 1 < FE) {
            STAGE_W(fe + 1, buf ^ 1);          // glds first (oldest in queue)
            LOAD_A(fe + 1);                    // A gathers stay in flight
        }
#pragma unroll
        for (int ks = 0; ks < 2; ++ks) {
            const bf16x8 a = ks ? af1 : af0;
            const int off = ks * 64 + lhi * 16;
#pragma unroll
            for (int fn = 0; fn < 8; ++fn) {
                const int col = fn * 16 + l15;
                const bf16x8 b = *(const bf16x8*)(
                    (const char*)&sW[buf][0] + col * 128 + (off ^ ((col & 7) << 4)));
                acc[fn] = __builtin_amdgcn_mfma_f32_16x16x32_bf16(a, b, acc[fn], 0, 0, 0);
            }
        }
        if (fe + 1 < FE) {
            asm volatile("s_waitcnt vmcnt(4)" ::: "memory");  // drain W stage only
            __syncthreads();
        }
    }

    // ---- epilogue: nontemporal stores (don't evict gather lines from L2/L3)
#pragma unroll
    for (int fn = 0; fn < 8; ++fn)
#pragma unroll
        for (int j = 0; j < 4; ++j) {
            const int row = bRow + wave * 16 + lhi * 4 + j;
            const int col = fn * 16 + l15;
            __builtin_nontemporal_store(acc[fn][j], out + (size_t)row * NF + col);
        }

#undef LOAD_A
#undef STAGE_W
#undef CONV_A
}

extern "C" void kernel_launch(void* const* d_in, const int* in_sizes, int n_in,
                              void* d_out, int out_size, void* d_ws, size_t ws_size,
                              hipStream_t stream) {
    const float* fine = (const float*)d_in[0];
    const int*   nbr  = (const int*)d_in[1];
    const float* w    = (const float*)d_in[2];
    float* out = (float*)d_out;

    unsigned short* wTswz = (unsigned short*)d_ws;   // FE*8192 ushorts = 144 KB

    prep_wt_kernel<<<(FE * 8192 + 255) / 256, 256, 0, stream>>>(w, wTswz);
    coarsen_kernel<<<N_COARSE / BM, THREADS, 0, stream>>>(fine, nbr, wTswz, out);
}